// Round 1
// baseline (11898.676 us; speedup 1.0000x reference)
//
#include <hip/hip_runtime.h>
#include <hip/hip_bf16.h>
#include <stdint.h>

// DeepAR decoder: L=3, B=512, H=1024, TAU=96, T=8, BETA=2
// ws layout (bytes):
//   Wih_b  bf16 [3][4096][1024]   @ 0          (25165824)
//   Whh_b  bf16 [3][4096][1024]   @ 25165824   (25165824)
//   h_b    bf16 [3][512][1024]    @ 50331648   (3145728)
//   c_s    f32  [3][512][1024]    @ 53477376   (6291456)
//   gbufT  f32  [3][4096][512]    @ 59768832   (25165824)
//   bias   f32  [3][4096]         @ 84934656   (49152)
//   macc   f32  [512][96][16]     @ 84983808   (3145728)
// total 88129536 B (~84 MB)

typedef __attribute__((ext_vector_type(8))) short short8;
typedef __attribute__((ext_vector_type(8))) __bf16 bf16x8_t;
typedef __attribute__((ext_vector_type(4))) float f32x4;
typedef __attribute__((ext_vector_type(4))) unsigned short u16x4;

static __device__ __forceinline__ unsigned short f2bf(float f) {
  unsigned int u = __float_as_uint(f);
  u += 0x7FFFu + ((u >> 16) & 1u);  // RNE
  return (unsigned short)(u >> 16);
}

static __device__ __forceinline__ float sigm(float x) {
  return 1.0f / (1.0f + __expf(-x));
}
static __device__ __forceinline__ float tanh_f(float x) {
  float xc = fminf(fmaxf(x, -15.f), 15.f);
  float e = __expf(2.0f * xc);
  return 1.0f - 2.0f / (e + 1.0f);
}

static __device__ __forceinline__ void gload_lds16(const void* g, void* l) {
  __builtin_amdgcn_global_load_lds(
      (const __attribute__((address_space(1))) unsigned int*)g,
      (__attribute__((address_space(3))) unsigned int*)l, 16, 0, 0);
}

static __device__ __forceinline__ f32x4 mfma16(short8 a, short8 b, f32x4 c) {
  return __builtin_amdgcn_mfma_f32_16x16x32_bf16((bf16x8_t)a, (bf16x8_t)b, c, 0, 0, 0);
}

// ---------------------------------------------------------------------------
// phase kernel: even blocks = x-GEMM(K=1024)+LSTM-cell epilogue for layer l;
// odd blocks = recurrent partial h_l'(.)·Whh_l'^T -> gbufT[l'] for next phase.
// WG tile: 64 batch x (4 gates x 32 h-cols). 4 waves, wave = gate.
// ---------------------------------------------------------------------------
__global__ __launch_bounds__(256, 2) void phase_kernel(
    const unsigned short* __restrict__ Wx,    // Wih_b[l]  [4096][1024]
    const unsigned short* __restrict__ xsrc,  // [512][1024] bf16
    const float* __restrict__ gb_rd,          // gbufT[l]  [4096][512]
    float* __restrict__ c_l,                  // [512][1024]
    unsigned short* __restrict__ h_out,       // [512][1024] bf16
    const float* __restrict__ bias_l,         // [4096]
    int do_proj, int step, float* __restrict__ macc,
    const float* __restrict__ W1, const float* __restrict__ W2,
    const unsigned short* __restrict__ Wh,    // Whh_b[lh]
    const unsigned short* __restrict__ hsrc,  // h_b[lh]
    float* __restrict__ gb_wr,                // gbufT[lh]
    int do_x, int do_h) {
  __shared__ __align__(16) char ldsA[2][4096];   // A tile 64x32 bf16, dbuf
  __shared__ __align__(16) float xchg[128 * 68]; // gate exchange / proj reduce

  const int bi = blockIdx.x;
  const int role = bi & 1;  // 0 = x-GEMM+epilogue, 1 = recurrent partial
  const int tile = bi >> 1;
  const int m0 = (tile >> 5) * 64;
  const int hc0 = (tile & 31) * 32;

  if (role == 0) { if (!do_x) return; } else { if (!do_h) return; }

  const unsigned short* A = role ? hsrc : xsrc;
  const unsigned short* W = role ? Wh : Wx;

  const int tid = threadIdx.x;
  const int w = tid >> 6;       // wave = gate index
  const int lane = tid & 63;
  const int quad = lane >> 4;
  const int l16 = lane & 15;

  // B row pointers (weights, row-major N x K, direct-to-register loads)
  const unsigned short* brow0 =
      W + (size_t)(w * 1024 + hc0 + l16) * 1024 + quad * 8;
  const unsigned short* brow1 = brow0 + 16 * 1024;

  // A staging: wave w stages rows [w*16, w*16+16), XOR-swizzled 16B chunks
  const int r_st = w * 16 + (lane >> 2);
  const int chunk = (lane & 3) ^ ((r_st >> 1) & 3);
  const unsigned short* gA = A + (size_t)(m0 + r_st) * 1024 + chunk * 8;
  char* lbase0 = &ldsA[0][w * 1024];
  char* lbase1 = &ldsA[1][w * 1024];

  // A fragment LDS offsets (undo swizzle)
  int aoff[4];
#pragma unroll
  for (int mb = 0; mb < 4; ++mb) {
    int r = mb * 16 + l16;
    aoff[mb] = r * 64 + ((quad ^ ((r >> 1) & 3)) * 16);
  }

  // issue first stage + depth-2 B prefetch before acc init
  gload_lds16(gA, lbase0);
  short8 breg[2][2];
  breg[0][0] = *(const short8*)(brow0);
  breg[0][1] = *(const short8*)(brow1);
  breg[1][0] = *(const short8*)(brow0 + 32);
  breg[1][1] = *(const short8*)(brow1 + 32);

  f32x4 acc[4][2];
  if (role == 0) {
#pragma unroll
    for (int mb = 0; mb < 4; ++mb)
#pragma unroll
      for (int nb = 0; nb < 2; ++nb) {
        int n = w * 1024 + hc0 + nb * 16 + l16;
        int m = m0 + mb * 16 + quad * 4;
        acc[mb][nb] = *(const f32x4*)(gb_rd + (size_t)n * 512 + m);
      }
  } else {
    f32x4 z4 = {0.f, 0.f, 0.f, 0.f};
#pragma unroll
    for (int mb = 0; mb < 4; ++mb)
#pragma unroll
      for (int nb = 0; nb < 2; ++nb) acc[mb][nb] = z4;
  }

#pragma unroll 4
  for (int i = 0; i < 32; ++i) {
    __syncthreads();  // A(i) staged, B(i) in regs
    int inext = (i + 1 < 32) ? (i + 1) : 31;           // harmless restage at end
    gload_lds16(gA + inext * 32, (i & 1) ? lbase0 : lbase1);
    int ipf = (i + 2 < 32) ? (i + 2) : 31;
    short8 pf0 = *(const short8*)(brow0 + ipf * 32);
    short8 pf1 = *(const short8*)(brow1 + ipf * 32);

    const char* lb = ldsA[i & 1];
    short8 a0 = *(const short8*)(lb + aoff[0]);
    short8 a1 = *(const short8*)(lb + aoff[1]);
    short8 a2 = *(const short8*)(lb + aoff[2]);
    short8 a3 = *(const short8*)(lb + aoff[3]);
    short8 bc0 = breg[i & 1][0], bc1 = breg[i & 1][1];

    acc[0][0] = mfma16(a0, bc0, acc[0][0]);
    acc[1][0] = mfma16(a1, bc0, acc[1][0]);
    acc[2][0] = mfma16(a2, bc0, acc[2][0]);
    acc[3][0] = mfma16(a3, bc0, acc[3][0]);
    acc[0][1] = mfma16(a0, bc1, acc[0][1]);
    acc[1][1] = mfma16(a1, bc1, acc[1][1]);
    acc[2][1] = mfma16(a2, bc1, acc[2][1]);
    acc[3][1] = mfma16(a3, bc1, acc[3][1]);

    breg[i & 1][0] = pf0;
    breg[i & 1][1] = pf1;
  }

  if (role == 1) {
    // store recurrent partial, transposed layout gbufT[n][m]
#pragma unroll
    for (int mb = 0; mb < 4; ++mb)
#pragma unroll
      for (int nb = 0; nb < 2; ++nb) {
        int n = w * 1024 + hc0 + nb * 16 + l16;
        int m = m0 + mb * 16 + quad * 4;
        *(f32x4*)(gb_wr + (size_t)n * 512 + m) = acc[mb][nb];
      }
    return;
  }

  // ---- x-role epilogue: gates -> (c,h) ----
  float bias0 = bias_l[w * 1024 + hc0 + l16];
  float bias1 = bias_l[w * 1024 + hc0 + 16 + l16];
#pragma unroll
  for (int mb = 0; mb < 4; ++mb) {
    f32x4 v0 = acc[mb][0] + bias0;
    f32x4 v1 = acc[mb][1] + bias1;
    *(f32x4*)&xchg[(w * 32 + l16) * 68 + mb * 16 + quad * 4] = v0;
    *(f32x4*)&xchg[(w * 32 + 16 + l16) * 68 + mb * 16 + quad * 4] = v1;
  }
  __syncthreads();

  const int m = tid & 63;
  const int hb = tid >> 6;
  const int colg = hc0 + hb * 8;
  float* cptr = c_l + (size_t)(m0 + m) * 1024 + colg;
  f32x4 co0 = *(const f32x4*)(cptr);
  f32x4 co1 = *(const f32x4*)(cptr + 4);
  float hv[8];
  f32x4 cn0, cn1;
#pragma unroll
  for (int j = 0; j < 8; ++j) {
    int cc = hb * 8 + j;
    float gi = xchg[(cc)*68 + m];
    float gf = xchg[(32 + cc) * 68 + m];
    float gg = xchg[(64 + cc) * 68 + m];
    float go = xchg[(96 + cc) * 68 + m];
    float co = (j < 4) ? co0[j] : co1[j - 4];
    float cn = sigm(gf) * co + sigm(gi) * tanh_f(gg);
    if (j < 4) cn0[j] = cn; else cn1[j - 4] = cn;
    hv[j] = sigm(go) * tanh_f(cn);
  }
  *(f32x4*)(cptr) = cn0;
  *(f32x4*)(cptr + 4) = cn1;
  short8 hpack;
#pragma unroll
  for (int j = 0; j < 8; ++j) hpack[j] = (short)f2bf(hv[j]);
  *(short8*)(h_out + (size_t)(m0 + m) * 1024 + colg) = hpack;

  if (do_proj) {
    // fused projection: partial dots over this WG's 32 h-cols
    float pm[8], ps[8];
#pragma unroll
    for (int t = 0; t < 8; ++t) {
      const f32x4* w1p = (const f32x4*)(W1 + t * 1024 + colg);
      const f32x4* w2p = (const f32x4*)(W2 + t * 1024 + colg);
      f32x4 wa = w1p[0], wb = w1p[1], wc = w2p[0], wd = w2p[1];
      float s1 = 0.f, s2 = 0.f;
#pragma unroll
      for (int j = 0; j < 4; ++j) {
        s1 += hv[j] * wa[j] + hv[4 + j] * wb[j];
        s2 += hv[j] * wc[j] + hv[4 + j] * wd[j];
      }
      pm[t] = s1;
      ps[t] = s2;
    }
    __syncthreads();            // done reading gate exchange
    float* proj = xchg;         // reuse as [4][64][17]
#pragma unroll
    for (int t = 0; t < 8; ++t) {
      proj[hb * 1088 + m * 17 + t] = pm[t];
      proj[hb * 1088 + m * 17 + 8 + t] = ps[t];
    }
    __syncthreads();
#pragma unroll
    for (int q = 0; q < 4; ++q) {
      int s = hb * 4 + q;
      float v = proj[m * 17 + s] + proj[1088 + m * 17 + s] +
                proj[2 * 1088 + m * 17 + s] + proj[3 * 1088 + m * 17 + s];
      atomicAdd(&macc[((size_t)(m0 + m) * 96 + step) * 16 + s], v);
    }
  }
}

// ---------------------------------------------------------------------------
__global__ void conv_w(const f32x4* __restrict__ wi, const f32x4* __restrict__ wh,
                       u16x4* __restrict__ wib, u16x4* __restrict__ whb) {
  int i = blockIdx.x * 256 + threadIdx.x;  // 3145728 vec4
  f32x4 a = wi[i], b = wh[i];
  u16x4 pa, pb;
#pragma unroll
  for (int j = 0; j < 4; ++j) {
    pa[j] = f2bf(a[j]);
    pb[j] = f2bf(b[j]);
  }
  wib[i] = pa;
  whb[i] = pb;
}

__global__ void init_state(const f32x4* __restrict__ hid, const f32x4* __restrict__ cel,
                           const f32x4* __restrict__ bih, const f32x4* __restrict__ bhh,
                           u16x4* __restrict__ hb, f32x4* __restrict__ cs,
                           f32x4* __restrict__ bias) {
  int i = blockIdx.x * 256 + threadIdx.x;  // 393216 vec4
  f32x4 h = hid[i];
  u16x4 p;
#pragma unroll
  for (int j = 0; j < 4; ++j) p[j] = f2bf(h[j]);
  hb[i] = p;
  cs[i] = cel[i];
  if (i < 3072) bias[i] = bih[i] + bhh[i];
}

__global__ void finalize_k(const float* __restrict__ macc, const float* __restrict__ b1,
                           const float* __restrict__ b2, float* __restrict__ out) {
  int idx = blockIdx.x * 256 + threadIdx.x;  // 393216 = 512*96*8
  int t = idx & 7;
  int bt = idx >> 3;  // b*96+tau
  float mu = macc[bt * 16 + t] + b1[t];
  float z2 = 2.0f * (macc[bt * 16 + 8 + t] + b2[t]);
  float sp = fmaxf(z2, 0.f) + log1pf(__expf(-fabsf(z2)));
  out[idx] = mu;
  out[393216 + idx] = 0.5f * sp;
}

// ---------------------------------------------------------------------------
extern "C" void kernel_launch(void* const* d_in, const int* in_sizes, int n_in,
                              void* d_out, int out_size, void* d_ws, size_t ws_size,
                              hipStream_t stream) {
  (void)in_sizes; (void)n_in; (void)out_size; (void)ws_size;
  const float* hidden = (const float*)d_in[0];
  const float* cell = (const float*)d_in[1];
  const float* Wih = (const float*)d_in[2];
  const float* Whh = (const float*)d_in[3];
  const float* bih = (const float*)d_in[4];
  const float* bhh = (const float*)d_in[5];
  const float* W1 = (const float*)d_in[6];
  const float* b1 = (const float*)d_in[7];
  const float* W2 = (const float*)d_in[8];
  const float* b2 = (const float*)d_in[9];
  float* out = (float*)d_out;

  char* ws = (char*)d_ws;
  unsigned short* Wih_b = (unsigned short*)(ws);
  unsigned short* Whh_b = (unsigned short*)(ws + 25165824);
  unsigned short* h_b = (unsigned short*)(ws + 50331648);
  float* c_s = (float*)(ws + 53477376);
  float* gbufT = (float*)(ws + 59768832);
  float* bias = (float*)(ws + 84934656);
  float* macc = (float*)(ws + 84983808);

  hipMemsetAsync(macc, 0, 3145728, stream);
  conv_w<<<12288, 256, 0, stream>>>((const f32x4*)Wih, (const f32x4*)Whh,
                                    (u16x4*)Wih_b, (u16x4*)Whh_b);
  init_state<<<1536, 256, 0, stream>>>((const f32x4*)hidden, (const f32x4*)cell,
                                       (const f32x4*)bih, (const f32x4*)bhh,
                                       (u16x4*)h_b, (f32x4*)c_s, (f32x4*)bias);

  // bootstrap: gbufT[0] = h0(-1) . Whh0^T  (h-role only)
  phase_kernel<<<512, 256, 0, stream>>>(Wih_b, h_b, gbufT, c_s, h_b, bias, 0, 0,
                                        macc, W1, W2, Whh_b, h_b, gbufT,
                                        /*do_x=*/0, /*do_h=*/1);

  for (int t = 0; t < 96; ++t) {
    for (int l = 0; l < 3; ++l) {
      int lh = (l + 1) % 3;
      int do_h = (t == 95 && l == 2) ? 0 : 1;
      const unsigned short* xsrc =
          h_b + (size_t)((l == 0) ? 2 : (l - 1)) * 524288;
      phase_kernel<<<512, 256, 0, stream>>>(
          Wih_b + (size_t)l * 4194304, xsrc, gbufT + (size_t)l * 2097152,
          c_s + (size_t)l * 524288, h_b + (size_t)l * 524288, bias + l * 4096,
          (l == 2) ? 1 : 0, t, macc, W1, W2, Whh_b + (size_t)lh * 4194304,
          h_b + (size_t)lh * 524288, gbufT + (size_t)lh * 2097152, /*do_x=*/1,
          do_h);
    }
  }
  finalize_k<<<1536, 256, 0, stream>>>(macc, b1, b2, out);
}

// Round 2
// 10224.976 us; speedup vs baseline: 1.1637x; 1.1637x over previous
//
#include <hip/hip_runtime.h>
#include <hip/hip_bf16.h>
#include <stdint.h>

// DeepAR decoder: L=3, B=512, H=1024, TAU=96, T=8, BETA=2
// ws layout (bytes):
//   Wih_b  bf16 [3][4096][1024]   @ 0          (25165824)
//   Whh_b  bf16 [3][4096][1024]   @ 25165824   (25165824)
//   h_b    bf16 [3][512][1024]    @ 50331648   (3145728)
//   c_s    f32  [3][512][1024]    @ 53477376   (6291456)
//   gbuf   f32  [3][8M]           @ 59768832   (25165824)  (MFMA C-layout tiles)
//   bias   f32  [3][4096]         @ 84934656   (49152)
//   macc   f32  [512][96][16]     @ 84983808   (3145728)

typedef __attribute__((ext_vector_type(8))) short short8;
typedef __attribute__((ext_vector_type(8))) __bf16 bf16x8_t;
typedef __attribute__((ext_vector_type(4))) float f32x4;
typedef __attribute__((ext_vector_type(4))) unsigned short u16x4;

static __device__ __forceinline__ unsigned short f2bf(float f) {
  unsigned int u = __float_as_uint(f);
  u += 0x7FFFu + ((u >> 16) & 1u);  // RNE
  return (unsigned short)(u >> 16);
}

static __device__ __forceinline__ float sigm(float x) {
  return 1.0f / (1.0f + __expf(-x));
}
static __device__ __forceinline__ float tanh_f(float x) {
  float xc = fminf(fmaxf(x, -15.f), 15.f);
  float e = __expf(2.0f * xc);
  return 1.0f - 2.0f / (e + 1.0f);
}

static __device__ __forceinline__ void gload_lds16(const void* g, void* l) {
  __builtin_amdgcn_global_load_lds(
      (const __attribute__((address_space(1))) unsigned int*)g,
      (__attribute__((address_space(3))) unsigned int*)l, 16, 0, 0);
}

static __device__ __forceinline__ f32x4 mfma16(short8 a, short8 b, f32x4 c) {
  return __builtin_amdgcn_mfma_f32_16x16x32_bf16((bf16x8_t)a, (bf16x8_t)b, c, 0, 0, 0);
}

// ---------------------------------------------------------------------------
// phase kernel, grid 256, 256 thr, 1 block/CU.
//   even blocks: x-GEMM(K=1024) + in-register LSTM cell epilogue for layer l
//   odd  blocks: recurrent partial h_lh . Whh_lh^T -> gbuf[lh]
// WG tile: 64 batch x (4 gates x 64 h-cols). Wave w owns h-cols [hc0+w*16, +16)
// for ALL 4 gates -> i,f,g,o land in the same lane (no LDS gate exchange).
// K-loop: BK=256 LDS chunks (dbuf, 3 barriers total), B direct-to-reg depth-2.
// ---------------------------------------------------------------------------
__global__ __launch_bounds__(256, 1) void phase_kernel(
    const unsigned short* __restrict__ Wx,    // Wih_b[l]  [4096][1024]
    const unsigned short* __restrict__ xsrc,  // [512][1024] bf16
    const float* __restrict__ gb_rd,          // gbuf[l]
    float* __restrict__ c_l,                  // [512][1024]
    unsigned short* __restrict__ h_out,       // [512][1024] bf16
    const float* __restrict__ bias_l,         // [4096]
    int do_proj, int step, float* __restrict__ macc,
    const float* __restrict__ W1, const float* __restrict__ W2,
    const unsigned short* __restrict__ Wh,    // Whh_b[lh]
    const unsigned short* __restrict__ hsrc,  // h_b[lh]
    float* __restrict__ gb_wr,                // gbuf[lh]
    int do_x, int do_h) {
  __shared__ __align__(16) char ldsA[2][32768];  // A chunk 64x256 bf16, dbuf

  const int bi = blockIdx.x;
  const int role = bi & 1;
  const int tile = bi >> 1;  // 0..127
  const int m0 = (tile & 7) * 64;
  const int hc0 = (tile >> 3) * 64;

  if (role == 0) { if (!do_x) return; } else { if (!do_h) return; }

  const unsigned short* A = role ? hsrc : xsrc;
  const unsigned short* W = role ? Wh : Wx;

  const int tid = threadIdx.x;
  const int w = tid >> 6;  // wave id: h-col group
  const int lane = tid & 63;
  const int quad = lane >> 4;
  const int l16 = lane & 15;

  // B rows (weights, direct-to-register): gate g, col hc0 + w*16 + l16
  const unsigned short* brow[4];
#pragma unroll
  for (int g = 0; g < 4; ++g)
    brow[g] = W + (size_t)(g * 1024 + hc0 + w * 16 + l16) * 1024 + quad * 8;

  // A staging geometry: 256 thr x 16 B = 4 KB/issue, 8 issues per 32 KB chunk.
  // LDS slot (tid) = row j*8 + (tid>>5), pos tid&31; fetch chunk pos^(row&31).
  const int rbase = tid >> 5;  // 0..7
  const int spos = tid & 31;
  const int wvbase = (tid >> 6) * 1024;  // wave-uniform LDS offset within issue

  // A fragment LDS read offsets (undo swizzle): row mb*16+l16,
  // pos = (ks*4+quad) ^ ((mb&1)*16 + l16)
  const int rx0 = l16, rx1 = 16 + l16;

#define STAGE(kc_, buf_)                                                      \
  {                                                                           \
    _Pragma("unroll") for (int j = 0; j < 8; ++j) {                           \
      int r_ = j * 8 + rbase;                                                 \
      int c_ = spos ^ (r_ & 31);                                              \
      gload_lds16(A + (size_t)(m0 + r_) * 1024 + (kc_)*256 + c_ * 8,          \
                  &ldsA[buf_][j * 4096 + wvbase]);                            \
    }                                                                         \
  }

  // prologue: stage chunk 0, B prefetch depth 2, acc init
  STAGE(0, 0);
  short8 bfr[2][4];
#pragma unroll
  for (int g = 0; g < 4; ++g) {
    bfr[0][g] = *(const short8*)(brow[g]);
    bfr[1][g] = *(const short8*)(brow[g] + 32);
  }

  f32x4 acc[4][4];
  if (role == 0) {
#pragma unroll
    for (int mb = 0; mb < 4; ++mb)
#pragma unroll
      for (int g = 0; g < 4; ++g)
        acc[mb][g] = *(const f32x4*)(
            gb_rd + ((size_t)(tile * 4 + w) * 16 + g * 4 + mb) * 256 + lane * 4);
  } else {
    f32x4 z4 = {0.f, 0.f, 0.f, 0.f};
#pragma unroll
    for (int mb = 0; mb < 4; ++mb)
#pragma unroll
      for (int g = 0; g < 4; ++g) acc[mb][g] = z4;
  }
  __syncthreads();  // chunk 0 staged

#pragma unroll
  for (int kc = 0; kc < 4; ++kc) {
    if (kc < 3) STAGE(kc + 1, (kc + 1) & 1);
    const char* base = ldsA[kc & 1];
    short8 afr[2][4];
#pragma unroll
    for (int mb = 0; mb < 4; ++mb) {
      int rxm = (mb & 1) ? rx1 : rx0;
      afr[0][mb] =
          *(const short8*)(base + (mb * 16 + l16) * 512 + ((quad ^ rxm) << 4));
    }
#pragma unroll
    for (int ks = 0; ks < 8; ++ks) {
      const int kg = kc * 8 + ks;
      short8 a0 = afr[ks & 1][0], a1 = afr[ks & 1][1];
      short8 a2 = afr[ks & 1][2], a3 = afr[ks & 1][3];
      short8 b0 = bfr[kg & 1][0], b1 = bfr[kg & 1][1];
      short8 b2 = bfr[kg & 1][2], b3 = bfr[kg & 1][3];
      if (ks < 7) {
#pragma unroll
        for (int mb = 0; mb < 4; ++mb) {
          int rxm = (mb & 1) ? rx1 : rx0;
          afr[(ks + 1) & 1][mb] =
              *(const short8*)(base + (mb * 16 + l16) * 512 +
                               ((((ks + 1) * 4 + quad) ^ rxm) << 4));
        }
      }
      if (kg + 2 < 32) {
#pragma unroll
        for (int g = 0; g < 4; ++g)
          bfr[kg & 1][g] = *(const short8*)(brow[g] + (kg + 2) * 32);
      }
      acc[0][0] = mfma16(a0, b0, acc[0][0]);
      acc[1][0] = mfma16(a1, b0, acc[1][0]);
      acc[2][0] = mfma16(a2, b0, acc[2][0]);
      acc[3][0] = mfma16(a3, b0, acc[3][0]);
      acc[0][1] = mfma16(a0, b1, acc[0][1]);
      acc[1][1] = mfma16(a1, b1, acc[1][1]);
      acc[2][1] = mfma16(a2, b1, acc[2][1]);
      acc[3][1] = mfma16(a3, b1, acc[3][1]);
      acc[0][2] = mfma16(a0, b2, acc[0][2]);
      acc[1][2] = mfma16(a1, b2, acc[1][2]);
      acc[2][2] = mfma16(a2, b2, acc[2][2]);
      acc[3][2] = mfma16(a3, b2, acc[3][2]);
      acc[0][3] = mfma16(a0, b3, acc[0][3]);
      acc[1][3] = mfma16(a1, b3, acc[1][3]);
      acc[2][3] = mfma16(a2, b3, acc[2][3]);
      acc[3][3] = mfma16(a3, b3, acc[3][3]);
    }
    if (kc < 3) __syncthreads();
  }
#undef STAGE

  if (role == 1) {
    // store recurrent partial in MFMA C-layout (coalesced 1 KB/instr)
#pragma unroll
    for (int mb = 0; mb < 4; ++mb)
#pragma unroll
      for (int g = 0; g < 4; ++g)
        *(f32x4*)(gb_wr + ((size_t)(tile * 4 + w) * 16 + g * 4 + mb) * 256 +
                  lane * 4) = acc[mb][g];
    return;
  }

  // ---- x-role epilogue: all 4 gates in-lane -> c,h (register only) ----
  const int colh = hc0 + w * 16 + l16;
  float bs0 = bias_l[colh];
  float bs1 = bias_l[1024 + colh];
  float bs2 = bias_l[2048 + colh];
  float bs3 = bias_l[3072 + colh];
  float hv[16];
#pragma unroll
  for (int mb = 0; mb < 4; ++mb) {
#pragma unroll
    for (int rr = 0; rr < 4; ++rr) {
      int row = m0 + mb * 16 + quad * 4 + rr;
      float gi = acc[mb][0][rr] + bs0;
      float gf = acc[mb][1][rr] + bs1;
      float gg = acc[mb][2][rr] + bs2;
      float go = acc[mb][3][rr] + bs3;
      float* cp = c_l + (size_t)row * 1024 + colh;
      float cn = sigm(gf) * (*cp) + sigm(gi) * tanh_f(gg);
      *cp = cn;
      float h = sigm(go) * tanh_f(cn);
      hv[mb * 4 + rr] = h;
      h_out[(size_t)row * 1024 + colh] = f2bf(h);
    }
  }

  if (do_proj) {
    // fused projection over this WG's 64 h-cols. LDS buffers reuse dead A bufs:
    // hbuf [64][65] f32 in buf0 (safe: buf0 dead since end-of-kc2 barrier),
    // projred [4][64][17] f32 in buf1 (written only after syncthreads).
    float* hbuf = (float*)ldsA[0];
    float* projred = (float*)ldsA[1];
#pragma unroll
    for (int mb = 0; mb < 4; ++mb)
#pragma unroll
      for (int rr = 0; rr < 4; ++rr)
        hbuf[(mb * 16 + quad * 4 + rr) * 65 + w * 16 + l16] = hv[mb * 4 + rr];
    __syncthreads();  // hbuf visible; all waves done with buf1 A-reads

    const int m = tid & 63;
    const int grp = tid >> 6;  // 16-col group
    float pm[8], ps[8];
    float hj[16];
#pragma unroll
    for (int j = 0; j < 16; ++j) hj[j] = hbuf[m * 65 + grp * 16 + j];
#pragma unroll
    for (int t = 0; t < 8; ++t) {
      const f32x4* w1p = (const f32x4*)(W1 + t * 1024 + hc0 + grp * 16);
      const f32x4* w2p = (const f32x4*)(W2 + t * 1024 + hc0 + grp * 16);
      float s1 = 0.f, s2 = 0.f;
#pragma unroll
      for (int v = 0; v < 4; ++v) {
        f32x4 wa = w1p[v], wb = w2p[v];
#pragma unroll
        for (int j = 0; j < 4; ++j) {
          s1 += hj[v * 4 + j] * wa[j];
          s2 += hj[v * 4 + j] * wb[j];
        }
      }
      pm[t] = s1;
      ps[t] = s2;
    }
#pragma unroll
    for (int t = 0; t < 8; ++t) {
      projred[(grp * 64 + m) * 17 + t] = pm[t];
      projred[(grp * 64 + m) * 17 + 8 + t] = ps[t];
    }
    __syncthreads();
#pragma unroll
    for (int q = 0; q < 4; ++q) {
      int s = grp * 4 + q;
      float v = projred[m * 17 + s] + projred[(64 + m) * 17 + s] +
                projred[(128 + m) * 17 + s] + projred[(192 + m) * 17 + s];
      atomicAdd(&macc[((size_t)(m0 + m) * 96 + step) * 16 + s], v);
    }
  }
}

// ---------------------------------------------------------------------------
__global__ void conv_w(const f32x4* __restrict__ wi, const f32x4* __restrict__ wh,
                       u16x4* __restrict__ wib, u16x4* __restrict__ whb) {
  int i = blockIdx.x * 256 + threadIdx.x;  // 3145728 vec4
  f32x4 a = wi[i], b = wh[i];
  u16x4 pa, pb;
#pragma unroll
  for (int j = 0; j < 4; ++j) {
    pa[j] = f2bf(a[j]);
    pb[j] = f2bf(b[j]);
  }
  wib[i] = pa;
  whb[i] = pb;
}

__global__ void init_state(const f32x4* __restrict__ hid, const f32x4* __restrict__ cel,
                           const f32x4* __restrict__ bih, const f32x4* __restrict__ bhh,
                           u16x4* __restrict__ hb, f32x4* __restrict__ cs,
                           f32x4* __restrict__ bias) {
  int i = blockIdx.x * 256 + threadIdx.x;  // 393216 vec4
  f32x4 h = hid[i];
  u16x4 p;
#pragma unroll
  for (int j = 0; j < 4; ++j) p[j] = f2bf(h[j]);
  hb[i] = p;
  cs[i] = cel[i];
  if (i < 3072) bias[i] = bih[i] + bhh[i];
}

__global__ void finalize_k(const float* __restrict__ macc, const float* __restrict__ b1,
                           const float* __restrict__ b2, float* __restrict__ out) {
  int idx = blockIdx.x * 256 + threadIdx.x;  // 393216 = 512*96*8
  int t = idx & 7;
  int bt = idx >> 3;  // b*96+tau
  float mu = macc[bt * 16 + t] + b1[t];
  float z2 = 2.0f * (macc[bt * 16 + 8 + t] + b2[t]);
  float sp = fmaxf(z2, 0.f) + log1pf(__expf(-fabsf(z2)));
  out[idx] = mu;
  out[393216 + idx] = 0.5f * sp;
}

// ---------------------------------------------------------------------------
extern "C" void kernel_launch(void* const* d_in, const int* in_sizes, int n_in,
                              void* d_out, int out_size, void* d_ws, size_t ws_size,
                              hipStream_t stream) {
  (void)in_sizes; (void)n_in; (void)out_size; (void)ws_size;
  const float* hidden = (const float*)d_in[0];
  const float* cell = (const float*)d_in[1];
  const float* Wih = (const float*)d_in[2];
  const float* Whh = (const float*)d_in[3];
  const float* bih = (const float*)d_in[4];
  const float* bhh = (const float*)d_in[5];
  const float* W1 = (const float*)d_in[6];
  const float* b1 = (const float*)d_in[7];
  const float* W2 = (const float*)d_in[8];
  const float* b2 = (const float*)d_in[9];
  float* out = (float*)d_out;

  char* ws = (char*)d_ws;
  unsigned short* Wih_b = (unsigned short*)(ws);
  unsigned short* Whh_b = (unsigned short*)(ws + 25165824);
  unsigned short* h_b = (unsigned short*)(ws + 50331648);
  float* c_s = (float*)(ws + 53477376);
  float* gbuf = (float*)(ws + 59768832);
  float* bias = (float*)(ws + 84934656);
  float* macc = (float*)(ws + 84983808);

  hipMemsetAsync(macc, 0, 3145728, stream);
  conv_w<<<12288, 256, 0, stream>>>((const f32x4*)Wih, (const f32x4*)Whh,
                                    (u16x4*)Wih_b, (u16x4*)Whh_b);
  init_state<<<1536, 256, 0, stream>>>((const f32x4*)hidden, (const f32x4*)cell,
                                       (const f32x4*)bih, (const f32x4*)bhh,
                                       (u16x4*)h_b, (f32x4*)c_s, (f32x4*)bias);

  // bootstrap: gbuf[0] = h0(-1) . Whh0^T  (h-role only)
  phase_kernel<<<256, 256, 0, stream>>>(Wih_b, h_b, gbuf, c_s, h_b, bias, 0, 0,
                                        macc, W1, W2, Whh_b, h_b, gbuf,
                                        /*do_x=*/0, /*do_h=*/1);

  for (int t = 0; t < 96; ++t) {
    for (int l = 0; l < 3; ++l) {
      int lh = (l + 1) % 3;
      int do_h = (t == 95 && l == 2) ? 0 : 1;
      const unsigned short* xsrc =
          h_b + (size_t)((l == 0) ? 2 : (l - 1)) * 524288;
      phase_kernel<<<256, 256, 0, stream>>>(
          Wih_b + (size_t)l * 4194304, xsrc, gbuf + (size_t)l * 2097152,
          c_s + (size_t)l * 524288, h_b + (size_t)l * 524288, bias + l * 4096,
          (l == 2) ? 1 : 0, t, macc, W1, W2, Whh_b + (size_t)lh * 4194304,
          h_b + (size_t)lh * 524288, gbuf + (size_t)lh * 2097152, /*do_x=*/1,
          do_h);
    }
  }
  finalize_k<<<1536, 256, 0, stream>>>(macc, b1, b2, out);
}

// Round 3
// 9692.435 us; speedup vs baseline: 1.2276x; 1.0549x over previous
//
#include <hip/hip_runtime.h>
#include <hip/hip_bf16.h>
#include <stdint.h>

// DeepAR decoder: L=3, B=512, H=1024, TAU=96, T=8, BETA=2
// ws layout (bytes):
//   Wih_b  bf16 [3][4096][1024]   @ 0          (25165824)
//   Whh_b  bf16 [3][4096][1024]   @ 25165824   (25165824)
//   h_b    bf16 [3][512][1024]    @ 50331648   (3145728)
//   c_s    f32  [3][512][1024]    @ 53477376   (6291456)
//   gbuf   f32  [3][8M]           @ 59768832   (25165824)  (MFMA C-layout tiles)
//   bias   f32  [3][4096]         @ 84934656   (49152)
//   macc   f32  [512][96][16]     @ 84983808   (3145728)

typedef __attribute__((ext_vector_type(8))) short short8;
typedef __attribute__((ext_vector_type(8))) __bf16 bf16x8_t;
typedef __attribute__((ext_vector_type(4))) float f32x4;
typedef __attribute__((ext_vector_type(4))) unsigned short u16x4;

static __device__ __forceinline__ unsigned short f2bf(float f) {
  unsigned int u = __float_as_uint(f);
  u += 0x7FFFu + ((u >> 16) & 1u);  // RNE
  return (unsigned short)(u >> 16);
}

static __device__ __forceinline__ float sigm(float x) {
  return 1.0f / (1.0f + __expf(-x));
}
static __device__ __forceinline__ float tanh_f(float x) {
  float xc = fminf(fmaxf(x, -15.f), 15.f);
  float e = __expf(2.0f * xc);
  return 1.0f - 2.0f / (e + 1.0f);
}

static __device__ __forceinline__ void gload_lds16(const void* g, void* l) {
  __builtin_amdgcn_global_load_lds(
      (const __attribute__((address_space(1))) unsigned int*)g,
      (__attribute__((address_space(3))) unsigned int*)l, 16, 0, 0);
}

static __device__ __forceinline__ f32x4 mfma16(short8 a, short8 b, f32x4 c) {
  return __builtin_amdgcn_mfma_f32_16x16x32_bf16((bf16x8_t)a, (bf16x8_t)b, c, 0, 0, 0);
}

// ---------------------------------------------------------------------------
// phase kernel, grid 256, 256 thr, 1 block/CU.
//   x-role blocks: x-GEMM(K=1024) + in-register LSTM cell epilogue for layer l
//   h-role blocks: recurrent partial h_lh . Whh_lh^T -> gbuf[lh]
// WG tile: 64 batch x (4 gates x 64 h-cols). Wave w owns h-cols [hc0+w*16,+16)
// for ALL 4 gates -> i,f,g,o land in the same lane (no LDS gate exchange).
// K-loop: BK=256 LDS chunks (dbuf, 3 barriers), B direct-to-reg depth-4.
//
// XCD-pinned swizzle (assumes XCD = blockIdx % 8 round-robin): all 8 m-tiles
// of a (role,hcg) pair map to one XCD -> the pair's 512 KB B-strip is read
// once from L3 and 7x from that XCD's L2; 4 pairs/XCD = 2 MB resident.
// x-role and h-role of the same hcg share the XCD -> gbuf handoff between
// consecutive dispatches is an L2 hit; c/h slices stay XCD-local.
// ---------------------------------------------------------------------------
__global__ __launch_bounds__(256, 1) void phase_kernel(
    const unsigned short* __restrict__ Wx,    // Wih_b[l]  [4096][1024]
    const unsigned short* __restrict__ xsrc,  // [512][1024] bf16
    const float* __restrict__ gb_rd,          // gbuf[l]
    float* __restrict__ c_l,                  // [512][1024]
    unsigned short* __restrict__ h_out,       // [512][1024] bf16
    const float* __restrict__ bias_l,         // [4096]
    int do_proj, int step, float* __restrict__ macc,
    const float* __restrict__ W1, const float* __restrict__ W2,
    const unsigned short* __restrict__ Wh,    // Whh_b[lh]
    const unsigned short* __restrict__ hsrc,  // h_b[lh]
    float* __restrict__ gb_wr,                // gbuf[lh]
    int do_x, int do_h) {
  __shared__ __align__(16) char ldsA[2][32768];  // A chunk 64x256 bf16, dbuf

  const int bi = blockIdx.x;
  // XCD-pinned decode: xcd = bi&7 owns pairs [4*xcd, 4*xcd+4)
  const int xcd = bi & 7;
  const int rslot = bi >> 3;              // 0..31
  const int pair = xcd * 4 + (rslot >> 3);  // 0..31
  const int mt = rslot & 7;               // m-tile 0..7
  const int role = pair & 1;              // 0 = x-GEMM+epilogue, 1 = h-partial
  const int hcg = pair >> 1;              // 0..15
  const int tile = hcg * 8 + mt;          // canonical tile id (gbuf layout)
  const int m0 = mt * 64;
  const int hc0 = hcg * 64;

  if (role == 0) { if (!do_x) return; } else { if (!do_h) return; }

  const unsigned short* A = role ? hsrc : xsrc;
  const unsigned short* W = role ? Wh : Wx;

  const int tid = threadIdx.x;
  const int w = tid >> 6;  // wave id: h-col group
  const int lane = tid & 63;
  const int quad = lane >> 4;
  const int l16 = lane & 15;

  // B rows (weights, direct-to-register): gate g, col hc0 + w*16 + l16
  const unsigned short* brow[4];
#pragma unroll
  for (int g = 0; g < 4; ++g)
    brow[g] = W + (size_t)(g * 1024 + hc0 + w * 16 + l16) * 1024 + quad * 8;

  // A staging geometry: 256 thr x 16 B = 4 KB/issue, 8 issues per 32 KB chunk.
  const int rbase = tid >> 5;  // 0..7
  const int spos = tid & 31;
  const int wvbase = (tid >> 6) * 1024;  // wave-uniform LDS offset within issue

  // A fragment LDS read offsets (undo swizzle)
  const int rx0 = l16, rx1 = 16 + l16;

#define STAGE(kc_, buf_)                                                      \
  {                                                                           \
    _Pragma("unroll") for (int j = 0; j < 8; ++j) {                           \
      int r_ = j * 8 + rbase;                                                 \
      int c_ = spos ^ (r_ & 31);                                              \
      gload_lds16(A + (size_t)(m0 + r_) * 1024 + (kc_)*256 + c_ * 8,          \
                  &ldsA[buf_][j * 4096 + wvbase]);                            \
    }                                                                         \
  }

  // prologue: stage chunk 0, B prefetch depth 4, acc init
  STAGE(0, 0);
  short8 bfr[4][4];
#pragma unroll
  for (int d = 0; d < 4; ++d)
#pragma unroll
    for (int g = 0; g < 4; ++g) bfr[d][g] = *(const short8*)(brow[g] + d * 32);

  f32x4 acc[4][4];
  if (role == 0) {
#pragma unroll
    for (int mb = 0; mb < 4; ++mb)
#pragma unroll
      for (int g = 0; g < 4; ++g)
        acc[mb][g] = *(const f32x4*)(
            gb_rd + ((size_t)(tile * 4 + w) * 16 + g * 4 + mb) * 256 + lane * 4);
  } else {
    f32x4 z4 = {0.f, 0.f, 0.f, 0.f};
#pragma unroll
    for (int mb = 0; mb < 4; ++mb)
#pragma unroll
      for (int g = 0; g < 4; ++g) acc[mb][g] = z4;
  }
  __syncthreads();  // chunk 0 staged

#pragma unroll
  for (int kc = 0; kc < 4; ++kc) {
    if (kc < 3) STAGE(kc + 1, (kc + 1) & 1);
    const char* base = ldsA[kc & 1];
    short8 afr[2][4];
#pragma unroll
    for (int mb = 0; mb < 4; ++mb) {
      int rxm = (mb & 1) ? rx1 : rx0;
      afr[0][mb] =
          *(const short8*)(base + (mb * 16 + l16) * 512 + ((quad ^ rxm) << 4));
    }
#pragma unroll
    for (int ks = 0; ks < 8; ++ks) {
      const int kg = kc * 8 + ks;
      short8 a0 = afr[ks & 1][0], a1 = afr[ks & 1][1];
      short8 a2 = afr[ks & 1][2], a3 = afr[ks & 1][3];
      short8 b0 = bfr[kg & 3][0], b1 = bfr[kg & 3][1];
      short8 b2 = bfr[kg & 3][2], b3 = bfr[kg & 3][3];
      if (ks < 7) {
#pragma unroll
        for (int mb = 0; mb < 4; ++mb) {
          int rxm = (mb & 1) ? rx1 : rx0;
          afr[(ks + 1) & 1][mb] =
              *(const short8*)(base + (mb * 16 + l16) * 512 +
                               ((((ks + 1) * 4 + quad) ^ rxm) << 4));
        }
      }
      if (kg + 4 < 32) {  // depth-4 B prefetch (~1240 cyc cover)
#pragma unroll
        for (int g = 0; g < 4; ++g)
          bfr[kg & 3][g] = *(const short8*)(brow[g] + (kg + 4) * 32);
      }
      acc[0][0] = mfma16(a0, b0, acc[0][0]);
      acc[1][0] = mfma16(a1, b0, acc[1][0]);
      acc[2][0] = mfma16(a2, b0, acc[2][0]);
      acc[3][0] = mfma16(a3, b0, acc[3][0]);
      acc[0][1] = mfma16(a0, b1, acc[0][1]);
      acc[1][1] = mfma16(a1, b1, acc[1][1]);
      acc[2][1] = mfma16(a2, b1, acc[2][1]);
      acc[3][1] = mfma16(a3, b1, acc[3][1]);
      acc[0][2] = mfma16(a0, b2, acc[0][2]);
      acc[1][2] = mfma16(a1, b2, acc[1][2]);
      acc[2][2] = mfma16(a2, b2, acc[2][2]);
      acc[3][2] = mfma16(a3, b2, acc[3][2]);
      acc[0][3] = mfma16(a0, b3, acc[0][3]);
      acc[1][3] = mfma16(a1, b3, acc[1][3]);
      acc[2][3] = mfma16(a2, b3, acc[2][3]);
      acc[3][3] = mfma16(a3, b3, acc[3][3]);
    }
    if (kc < 3) __syncthreads();
  }
#undef STAGE

  if (role == 1) {
    // store recurrent partial in MFMA C-layout (coalesced 1 KB/instr)
#pragma unroll
    for (int mb = 0; mb < 4; ++mb)
#pragma unroll
      for (int g = 0; g < 4; ++g)
        *(f32x4*)(gb_wr + ((size_t)(tile * 4 + w) * 16 + g * 4 + mb) * 256 +
                  lane * 4) = acc[mb][g];
    return;
  }

  // ---- x-role epilogue: all 4 gates in-lane -> c,h (register only) ----
  const int colh = hc0 + w * 16 + l16;
  float bs0 = bias_l[colh];
  float bs1 = bias_l[1024 + colh];
  float bs2 = bias_l[2048 + colh];
  float bs3 = bias_l[3072 + colh];
  float hv[16];
#pragma unroll
  for (int mb = 0; mb < 4; ++mb) {
#pragma unroll
    for (int rr = 0; rr < 4; ++rr) {
      int row = m0 + mb * 16 + quad * 4 + rr;
      float gi = acc[mb][0][rr] + bs0;
      float gf = acc[mb][1][rr] + bs1;
      float gg = acc[mb][2][rr] + bs2;
      float go = acc[mb][3][rr] + bs3;
      float* cp = c_l + (size_t)row * 1024 + colh;
      float cn = sigm(gf) * (*cp) + sigm(gi) * tanh_f(gg);
      *cp = cn;
      float h = sigm(go) * tanh_f(cn);
      hv[mb * 4 + rr] = h;
      h_out[(size_t)row * 1024 + colh] = f2bf(h);
    }
  }

  if (do_proj) {
    // fused projection over this WG's 64 h-cols; reuse dead A LDS buffers.
    float* hbuf = (float*)ldsA[0];
    float* projred = (float*)ldsA[1];
#pragma unroll
    for (int mb = 0; mb < 4; ++mb)
#pragma unroll
      for (int rr = 0; rr < 4; ++rr)
        hbuf[(mb * 16 + quad * 4 + rr) * 65 + w * 16 + l16] = hv[mb * 4 + rr];
    __syncthreads();

    const int m = tid & 63;
    const int grp = tid >> 6;  // 16-col group
    float pm[8], ps[8];
    float hj[16];
#pragma unroll
    for (int j = 0; j < 16; ++j) hj[j] = hbuf[m * 65 + grp * 16 + j];
#pragma unroll
    for (int t = 0; t < 8; ++t) {
      const f32x4* w1p = (const f32x4*)(W1 + t * 1024 + hc0 + grp * 16);
      const f32x4* w2p = (const f32x4*)(W2 + t * 1024 + hc0 + grp * 16);
      float s1 = 0.f, s2 = 0.f;
#pragma unroll
      for (int v = 0; v < 4; ++v) {
        f32x4 wa = w1p[v], wb = w2p[v];
#pragma unroll
        for (int j = 0; j < 4; ++j) {
          s1 += hj[v * 4 + j] * wa[j];
          s2 += hj[v * 4 + j] * wb[j];
        }
      }
      pm[t] = s1;
      ps[t] = s2;
    }
#pragma unroll
    for (int t = 0; t < 8; ++t) {
      projred[(grp * 64 + m) * 17 + t] = pm[t];
      projred[(grp * 64 + m) * 17 + 8 + t] = ps[t];
    }
    __syncthreads();
#pragma unroll
    for (int q = 0; q < 4; ++q) {
      int s = grp * 4 + q;
      float v = projred[m * 17 + s] + projred[(64 + m) * 17 + s] +
                projred[(128 + m) * 17 + s] + projred[(192 + m) * 17 + s];
      atomicAdd(&macc[((size_t)(m0 + m) * 96 + step) * 16 + s], v);
    }
  }
}

// ---------------------------------------------------------------------------
__global__ void conv_w(const f32x4* __restrict__ wi, const f32x4* __restrict__ wh,
                       u16x4* __restrict__ wib, u16x4* __restrict__ whb) {
  int i = blockIdx.x * 256 + threadIdx.x;  // 3145728 vec4
  f32x4 a = wi[i], b = wh[i];
  u16x4 pa, pb;
#pragma unroll
  for (int j = 0; j < 4; ++j) {
    pa[j] = f2bf(a[j]);
    pb[j] = f2bf(b[j]);
  }
  wib[i] = pa;
  whb[i] = pb;
}

__global__ void init_state(const f32x4* __restrict__ hid, const f32x4* __restrict__ cel,
                           const f32x4* __restrict__ bih, const f32x4* __restrict__ bhh,
                           u16x4* __restrict__ hb, f32x4* __restrict__ cs,
                           f32x4* __restrict__ bias) {
  int i = blockIdx.x * 256 + threadIdx.x;  // 393216 vec4
  f32x4 h = hid[i];
  u16x4 p;
#pragma unroll
  for (int j = 0; j < 4; ++j) p[j] = f2bf(h[j]);
  hb[i] = p;
  cs[i] = cel[i];
  if (i < 3072) bias[i] = bih[i] + bhh[i];
}

__global__ void finalize_k(const float* __restrict__ macc, const float* __restrict__ b1,
                           const float* __restrict__ b2, float* __restrict__ out) {
  int idx = blockIdx.x * 256 + threadIdx.x;  // 393216 = 512*96*8
  int t = idx & 7;
  int bt = idx >> 3;  // b*96+tau
  float mu = macc[bt * 16 + t] + b1[t];
  float z2 = 2.0f * (macc[bt * 16 + 8 + t] + b2[t]);
  float sp = fmaxf(z2, 0.f) + log1pf(__expf(-fabsf(z2)));
  out[idx] = mu;
  out[393216 + idx] = 0.5f * sp;
}

// ---------------------------------------------------------------------------
extern "C" void kernel_launch(void* const* d_in, const int* in_sizes, int n_in,
                              void* d_out, int out_size, void* d_ws, size_t ws_size,
                              hipStream_t stream) {
  (void)in_sizes; (void)n_in; (void)out_size; (void)ws_size;
  const float* hidden = (const float*)d_in[0];
  const float* cell = (const float*)d_in[1];
  const float* Wih = (const float*)d_in[2];
  const float* Whh = (const float*)d_in[3];
  const float* bih = (const float*)d_in[4];
  const float* bhh = (const float*)d_in[5];
  const float* W1 = (const float*)d_in[6];
  const float* b1 = (const float*)d_in[7];
  const float* W2 = (const float*)d_in[8];
  const float* b2 = (const float*)d_in[9];
  float* out = (float*)d_out;

  char* ws = (char*)d_ws;
  unsigned short* Wih_b = (unsigned short*)(ws);
  unsigned short* Whh_b = (unsigned short*)(ws + 25165824);
  unsigned short* h_b = (unsigned short*)(ws + 50331648);
  float* c_s = (float*)(ws + 53477376);
  float* gbuf = (float*)(ws + 59768832);
  float* bias = (float*)(ws + 84934656);
  float* macc = (float*)(ws + 84983808);

  hipMemsetAsync(macc, 0, 3145728, stream);
  conv_w<<<12288, 256, 0, stream>>>((const f32x4*)Wih, (const f32x4*)Whh,
                                    (u16x4*)Wih_b, (u16x4*)Whh_b);
  init_state<<<1536, 256, 0, stream>>>((const f32x4*)hidden, (const f32x4*)cell,
                                       (const f32x4*)bih, (const f32x4*)bhh,
                                       (u16x4*)h_b, (f32x4*)c_s, (f32x4*)bias);

  // bootstrap: gbuf[0] = h0(-1) . Whh0^T  (h-role only)
  phase_kernel<<<256, 256, 0, stream>>>(Wih_b, h_b, gbuf, c_s, h_b, bias, 0, 0,
                                        macc, W1, W2, Whh_b, h_b, gbuf,
                                        /*do_x=*/0, /*do_h=*/1);

  for (int t = 0; t < 96; ++t) {
    for (int l = 0; l < 3; ++l) {
      int lh = (l + 1) % 3;
      int do_h = (t == 95 && l == 2) ? 0 : 1;
      const unsigned short* xsrc =
          h_b + (size_t)((l == 0) ? 2 : (l - 1)) * 524288;
      phase_kernel<<<256, 256, 0, stream>>>(
          Wih_b + (size_t)l * 4194304, xsrc, gbuf + (size_t)l * 2097152,
          c_s + (size_t)l * 524288, h_b + (size_t)l * 524288, bias + l * 4096,
          (l == 2) ? 1 : 0, t, macc, W1, W2, Whh_b + (size_t)lh * 4194304,
          h_b + (size_t)lh * 524288, gbuf + (size_t)lh * 2097152, /*do_x=*/1,
          do_h);
    }
  }
  finalize_k<<<1536, 256, 0, stream>>>(macc, b1, b2, out);
}